// Round 1
// 286.193 us; speedup vs baseline: 1.0085x; 1.0085x over previous
//
#include <hip/hip_runtime.h>
#include <hip/hip_bf16.h>

// AttentivePredictionFusion: B=8, T=2048, D=512, H=128. fp32 in, fp32 out.
// R9: attn_fused PV step re-decomposed wave->d-split. Old: wave w owned Q rows
//     [16w,16w+16) and read the ENTIRE 256x64 V tile (32 b128/wave/ktile, 4x
//     duplication) -> LDS-port-bound (54 b128 reads vs 48 MFMA per wave-ktile,
//     MfmaUtil 20%, 1.4e7 bank-conflict cycles). New: QK^T stays row-split;
//     P goes through sP (now cross-wave, +1 barrier/ktile); PV: wave w computes
//     O[0:64][64w,64w+64) reading only its own 64 V rows (8 b128) + all sP
//     (8 b128). 54 -> 36 reads/wave/ktile. Rowsums exchanged via sRS at end.

#define APF_B 8
#define APF_T 2048
#define APF_D 512
#define APF_H 128
#define APF_M (APF_B * APF_T)   // 16384

typedef unsigned short u16;
typedef __attribute__((ext_vector_type(8))) short short8;
typedef __attribute__((ext_vector_type(4))) float f32x4;

static __device__ __forceinline__ float bf2f(u16 u) {
    union { unsigned int i; float f; } w;
    w.i = ((unsigned int)u) << 16;
    return w.f;
}
static __device__ __forceinline__ u16 f2bf(float x) {
    union { float f; unsigned int u; } cv;
    cv.f = x;
    unsigned int u = cv.u + 0x7FFFu + ((cv.u >> 16) & 1u);  // RNE
    return (u16)(u >> 16);
}

// async global->LDS, 16 B per lane; LDS dest = wave-uniform base + lane*16
static __device__ __forceinline__ void load16_lds(const u16* g, u16* l) {
    __builtin_amdgcn_global_load_lds(
        (const __attribute__((address_space(1))) unsigned int*)g,
        (__attribute__((address_space(3))) unsigned int*)l,
        16, 0, 0);
}

// ---------------- prep kernels ----------------

__global__ __launch_bounds__(256) void cvt_pair(const float* __restrict__ in0,
                                                u16* __restrict__ out0,
                                                const float* __restrict__ in1,
                                                u16* __restrict__ out1, long n4)
{
    long i = blockIdx.x * 256L + threadIdx.x;
    const long stride = (long)gridDim.x * 256L;
    for (; i < 2 * n4; i += stride) {
        const float* in = (i < n4) ? in0 : in1;
        u16* out = (i < n4) ? out0 : out1;
        const long j = (i < n4) ? i : (i - n4);
        const float4 v = ((const float4*)in)[j];
        ushort4 o;
        o.x = f2bf(v.x); o.y = f2bf(v.y); o.z = f2bf(v.z); o.w = f2bf(v.w);
        ((ushort4*)out)[j] = o;
    }
}

// weight transposes (fp32 [K][N] -> bf16 [N][K])
__global__ __launch_bounds__(256) void prep_weights(
    const float* __restrict__ Wq, u16* __restrict__ WqT,
    const float* __restrict__ Wk, u16* __restrict__ WkT,
    const float* __restrict__ Wv, u16* __restrict__ WvT,
    const float* __restrict__ Wf, u16* __restrict__ WfT)
{
    const long e = blockIdx.x * 256L + threadIdx.x;
    if (e < 65536) {
        const long idx = e;              // Wq: K=512,N=128
        const long n = idx / 512, k = idx % 512;
        WqT[idx] = f2bf(Wq[k * 128 + n]);
    } else if (e < 131072) {
        const long idx = e - 65536;      // Wk
        const long n = idx / 512, k = idx % 512;
        WkT[idx] = f2bf(Wk[k * 128 + n]);
    } else if (e < 393216) {
        const long idx = e - 131072;     // Wv: K=512,N=512
        const long n = idx / 512, k = idx % 512;
        WvT[idx] = f2bf(Wv[k * 512 + n]);
    } else if (e < 917504) {
        const long idx = e - 393216;     // Wf: K=1024,N=512
        const long n = idx / 1024, k = idx % 1024;
        WfT[idx] = f2bf(Wf[k * 512 + n]);
    }
}

// ---------------- MFMA GEMM (projections / fusion / vT) ----------------
// A: bf16 [M][K]; B: bf16 [N][K]. DUAL: 0 plain batched; 1 concat-A; 2 z-select.
// EPI: 0 bf16 store +bias; 2 fp32 sigmoid store +bias.
// BIASM: 0 bias indexed by n (output col); 1 bias indexed by m (output row).
template <int DUAL, int EPI, int BIASM>
__global__ __launch_bounds__(256) void mfma_gemm(
    const u16* __restrict__ Ap, const u16* __restrict__ A2p, long lda,
    const u16* __restrict__ Bp, const u16* __restrict__ Bp2, long ldb,
    const float* __restrict__ biasp, const float* __restrict__ bias2,
    void* __restrict__ Cp, void* __restrict__ Cp2, long ldc, int K,
    long sA, long sB, long sC)
{
    __shared__ u16 smA[128 * 32];
    __shared__ u16 smB[128 * 32];

    const int tid  = threadIdx.x;
    const int lane = tid & 63;
    const int wid  = tid >> 6;
    const int wr   = wid >> 1;
    const int wc   = wid & 1;

    const long row0 = (long)blockIdx.y * 128;
    const long col0 = (long)blockIdx.x * 128;
    const long z    = blockIdx.z;

    const u16* Abase = (DUAL == 2) ? (z ? A2p : Ap) : (Ap + z * sA);
    const u16* Bbase = (DUAL == 2) ? (z ? Bp2 : Bp) : (Bp + z * sB);

    f32x4 acc[4][4];
#pragma unroll
    for (int i = 0; i < 4; ++i)
#pragma unroll
        for (int j = 0; j < 4; ++j)
            acc[i][j] = (f32x4){0.f, 0.f, 0.f, 0.f};

    const int lrow = (lane >> 4) * 4;
    const int lcol = lane & 15;
    const int q8   = (lane >> 4) * 8;

    for (int kb = 0; kb < K; kb += 32) {
#pragma unroll
        for (int rep = 0; rep < 2; ++rep) {
            const int c  = tid + rep * 256;
            const int r  = c >> 2;
            const int kc = (c & 3) * 8;
            const int wbase = (wid * 64 + rep * 256) * 8;
            const u16* ga;
            if (DUAL == 1 && (kb + kc) >= APF_D) {
                ga = A2p + (row0 + r) * lda + (kb + kc - APF_D);
            } else {
                ga = Abase + (row0 + r) * lda + (kb + kc);
            }
            load16_lds(ga, &smA[wbase]);
            const u16* gb = Bbase + (col0 + r) * ldb + (kb + kc);
            load16_lds(gb, &smB[wbase]);
        }
        __syncthreads();

        short8 av[4], bv4[4];
#pragma unroll
        for (int ti = 0; ti < 4; ++ti)
            av[ti] = *(const short8*)&smA[(wr * 64 + ti * 16 + lcol) * 32 + q8];
#pragma unroll
        for (int tj = 0; tj < 4; ++tj)
            bv4[tj] = *(const short8*)&smB[(wc * 64 + tj * 16 + lcol) * 32 + q8];

#pragma unroll
        for (int ti = 0; ti < 4; ++ti)
#pragma unroll
            for (int tj = 0; tj < 4; ++tj)
                acc[ti][tj] = __builtin_amdgcn_mfma_f32_16x16x32_bf16(
                    av[ti], bv4[tj], acc[ti][tj], 0, 0, 0);
        __syncthreads();
    }

    const float* bias = (DUAL == 2 && z) ? bias2 : biasp;

#pragma unroll
    for (int ti = 0; ti < 4; ++ti) {
        const long m0t = row0 + wr * 64 + ti * 16 + lrow;
#pragma unroll
        for (int tj = 0; tj < 4; ++tj) {
            const long n = col0 + wc * 64 + tj * 16 + lcol;
            const float bn = (BIASM == 0 && bias != nullptr) ? bias[n] : 0.f;
            if (EPI == 0) {
                u16* C = (u16*)((DUAL == 2 && z) ? Cp2 : Cp) + ((DUAL == 2) ? 0 : z * sC);
#pragma unroll
                for (int r = 0; r < 4; ++r) {
                    const float bm = (BIASM == 1) ? bias[m0t + r] : bn;
                    C[(m0t + r) * ldc + n] = f2bf(acc[ti][tj][r] + bm);
                }
            } else {
                float* C = (float*)Cp;
#pragma unroll
                for (int r = 0; r < 4; ++r) {
                    const float val = acc[ti][tj][r] + bn;
                    C[(m0t + r) * ldc + n] = 1.0f / (1.0f + expf(-val));
                }
            }
        }
    }
}

// ---------------- fused attention ----------------
// Grid (D-chunks=2, Q-tiles=32, B=8) = 512 blocks; 256 threads = 4 waves.
// Block: Q rows [q0,q0+64), out cols [d0,d0+256). Per s-tile of 64:
//   QK^T: wave w computes S rows [16w,16w+16) (4 sQ + 16 sK b128 reads),
//   exp -> sP (cross-wave now), barrier,
//   PV:   wave w computes O[0:64][64w,64w+64) reading all sP rows (8 b128)
//         + only its own 64 sV rows (8 b128).  36 reads/wave/ktile vs the
//         old 54 (old PV read the whole 256x64 V tile per wave = 4x dup).
// Rowsums per-wave (own Q rows) -> sRS at end -> all waves normalize.
// LDS = 79.2 KB -> 2 blocks/CU.
#define FA_LDQ 136
#define FA_LDK 136
#define FA_LDV 72
#define FA_LDP 72

__global__ __launch_bounds__(256, 2) void attn_fused(
    const u16* __restrict__ qg, const u16* __restrict__ kg,
    const u16* __restrict__ vTg, u16* __restrict__ attg)
{
    __shared__ u16 sQ[64 * FA_LDQ];
    __shared__ u16 sK[64 * FA_LDK];
    __shared__ u16 sV[256 * FA_LDV];
    __shared__ u16 sP[64 * FA_LDP];
    __shared__ float sRS[64];

    const int tid  = threadIdx.x;
    const int lane = tid & 63;
    const int w    = tid >> 6;       // 0..3
    const int l15  = lane & 15;
    const int q4   = lane >> 4;      // 0..3

    const long z  = blockIdx.z;
    const long q0 = (long)blockIdx.y * 64;
    const long d0 = (long)blockIdx.x * 256;

    // stage Q tile once (contiguous 64x128 u16)
    {
        const u16* src = qg + (z * APF_T + q0) * APF_H;
#pragma unroll
        for (int rep = 0; rep < 4; ++rep) {
            const int c   = tid + rep * 256;      // 0..1023
            const int row = c >> 4;
            const int c8  = (c & 15) * 8;
            *(uint4*)&sQ[row * FA_LDQ + c8] = *(const uint4*)(src + (long)c * 8);
        }
    }

    f32x4 oacc[4][4];   // [q-tile ti][d-tile dt], O[0:64][w*64 + 0:64]
#pragma unroll
    for (int i = 0; i < 4; ++i)
#pragma unroll
        for (int j = 0; j < 4; ++j)
            oacc[i][j] = (f32x4){0.f, 0.f, 0.f, 0.f};
    float rs[4] = {0.f, 0.f, 0.f, 0.f};

    for (int kt = 0; kt < APF_T / 64; ++kt) {
        __syncthreads();   // prev iter's sK/sV/sP reads done (also covers sQ stage)
        // stage K tile (contiguous 64x128 u16)
        {
            const u16* src = kg + (z * APF_T + (long)kt * 64) * APF_H;
#pragma unroll
            for (int rep = 0; rep < 4; ++rep) {
                const int c   = tid + rep * 256;  // 0..1023
                const int row = c >> 4;
                const int c8  = (c & 15) * 8;
                *(uint4*)&sK[row * FA_LDK + c8] = *(const uint4*)(src + (long)c * 8);
            }
        }
        // stage V tile: sV[d][s] from vT[z][d0+d][kt*64+s]
        {
            const u16* src = vTg + z * ((long)APF_D * APF_T) + d0 * APF_T + (long)kt * 64;
#pragma unroll
            for (int rep = 0; rep < 8; ++rep) {
                const int c   = tid + rep * 256;  // 0..2047
                const int row = c >> 3;           // 0..255
                const int c8  = (c & 7) * 8;      // 0..56
                *(uint4*)&sV[row * FA_LDV + c8] =
                    *(const uint4*)(src + (long)row * APF_T + c8);
            }
        }
        __syncthreads();

        // S(16x64 per wave) = Q_w @ K_tile^T, contraction over h=128
        f32x4 sacc[4];
#pragma unroll
        for (int tj = 0; tj < 4; ++tj) sacc[tj] = (f32x4){0.f, 0.f, 0.f, 0.f};
#pragma unroll
        for (int kk = 0; kk < 4; ++kk) {
            const short8 av = *(const short8*)&sQ[(w * 16 + l15) * FA_LDQ + kk * 32 + q4 * 8];
#pragma unroll
            for (int tj = 0; tj < 4; ++tj) {
                const short8 bv = *(const short8*)&sK[(tj * 16 + l15) * FA_LDK + kk * 32 + q4 * 8];
                sacc[tj] = __builtin_amdgcn_mfma_f32_16x16x32_bf16(av, bv, sacc[tj], 0, 0, 0);
            }
        }
        // exp + rowsum + P to LDS (C-layout -> A-layout hop)
#pragma unroll
        for (int tj = 0; tj < 4; ++tj)
#pragma unroll
            for (int r = 0; r < 4; ++r) {
                const float e = __expf(sacc[tj][r]);
                rs[r] += e;
                sP[(w * 16 + q4 * 4 + r) * FA_LDP + tj * 16 + l15] = f2bf(e);
            }
        __syncthreads();   // sP visible to all waves

        // O[0:64][w*64 + 0:64] += P(64x64) @ V_w(64x64)^T
#pragma unroll
        for (int kk = 0; kk < 2; ++kk) {
            short8 ap[4];
#pragma unroll
            for (int ti = 0; ti < 4; ++ti)
                ap[ti] = *(const short8*)&sP[(ti * 16 + l15) * FA_LDP + kk * 32 + q4 * 8];
#pragma unroll
            for (int dt = 0; dt < 4; ++dt) {
                const short8 bv = *(const short8*)&sV[(w * 64 + dt * 16 + l15) * FA_LDV + kk * 32 + q4 * 8];
#pragma unroll
                for (int ti = 0; ti < 4; ++ti)
                    oacc[ti][dt] = __builtin_amdgcn_mfma_f32_16x16x32_bf16(
                        ap[ti], bv, oacc[ti][dt], 0, 0, 0);
            }
        }
    }

    // rowsum reduce across the 16 col-lanes (bits 0..3 of lane), publish 1/sum
#pragma unroll
    for (int r = 0; r < 4; ++r) {
        float s = rs[r];
        s += __shfl_xor(s, 1);
        s += __shfl_xor(s, 2);
        s += __shfl_xor(s, 4);
        s += __shfl_xor(s, 8);
        rs[r] = 1.0f / s;
    }
    if (l15 == 0) {
#pragma unroll
        for (int r = 0; r < 4; ++r)
            sRS[w * 16 + q4 * 4 + r] = rs[r];
    }
    __syncthreads();

    // store att rows: all 64 q rows x own 64 d cols
    const long rowbase = z * APF_T + q0;
#pragma unroll
    for (int ti = 0; ti < 4; ++ti) {
        float inv[4];
#pragma unroll
        for (int r = 0; r < 4; ++r)
            inv[r] = sRS[ti * 16 + q4 * 4 + r];
#pragma unroll
        for (int dt = 0; dt < 4; ++dt) {
            const long col = d0 + w * 64 + dt * 16 + l15;
#pragma unroll
            for (int r = 0; r < 4; ++r)
                attg[(rowbase + ti * 16 + q4 * 4 + r) * APF_D + col] =
                    f2bf(oacc[ti][dt][r] * inv[r]);
        }
    }
}

extern "C" void kernel_launch(void* const* d_in, const int* in_sizes, int n_in,
                              void* d_out, int out_size, void* d_ws, size_t ws_size,
                              hipStream_t stream)
{
    (void)in_sizes; (void)n_in; (void)out_size; (void)ws_size;

    const float* x    = (const float*)d_in[0];
    const float* pred = (const float*)d_in[1];
    const float* Wq   = (const float*)d_in[2];
    const float* bq   = (const float*)d_in[3];
    const float* Wk   = (const float*)d_in[4];
    const float* bk   = (const float*)d_in[5];
    const float* Wv   = (const float*)d_in[6];
    const float* bv   = (const float*)d_in[7];
    const float* Wf   = (const float*)d_in[8];
    const float* bfu  = (const float*)d_in[9];

    // Workspace (u16), ~80 MB
    u16* wsp   = (u16*)d_ws;
    u16* xb    = wsp;                                  // [16384][512]
    u16* predb = xb    + (long)APF_M * APF_D;          // [16384][512]
    u16* qb    = predb + (long)APF_M * APF_D;          // [16384][128]
    u16* kbuf  = qb    + (long)APF_M * APF_H;          // [16384][128]
    u16* vTb   = kbuf  + (long)APF_M * APF_H;          // [8][512][2048]
    u16* attb  = vTb   + (long)APF_M * APF_D;          // [16384][512]
    u16* WqT   = attb  + (long)APF_M * APF_D;          // [128][512]
    u16* WkT   = WqT   + (long)APF_H * APF_D;          // [128][512]
    u16* WvT   = WkT   + (long)APF_H * APF_D;          // [512][512]
    u16* WfT   = WvT   + (long)APF_D * APF_D;          // [512][1024]

    const dim3 thr(256);
    const long nBTD4 = (long)APF_M * APF_D / 4;

    cvt_pair<<<dim3(1024), thr, 0, stream>>>(x, xb, pred, predb, nBTD4);
    prep_weights<<<dim3(3584), thr, 0, stream>>>(Wq, WqT, Wk, WkT, Wv, WvT, Wf, WfT);

    // q = pred@Wq+bq (z=0), k = x@Wk+bk (z=1)
    mfma_gemm<2, 0, 0><<<dim3(1, 128, 2), thr, 0, stream>>>(
        predb, xb, APF_D, WqT, WkT, APF_D, bq, bk, qb, kbuf, APF_H, APF_D,
        0, 0, 0);

    // vT[z] = WvT @ xb[z]^T + bv  (A=WvT M=512-d, B=xb N=s; bias on M;
    //  coalesced store, ldc=2048)
    mfma_gemm<0, 0, 1><<<dim3(16, 4, 8), thr, 0, stream>>>(
        WvT, nullptr, APF_D, xb, nullptr, APF_D, bv, nullptr, vTb, nullptr,
        APF_T, APF_D, 0, (long)APF_T * APF_D, (long)APF_D * APF_T);

    // fused attention: att = softmax(q k^T) v   (one kernel, no scores buffer)
    attn_fused<<<dim3(2, 32, 8), thr, 0, stream>>>(qb, kbuf, vTb, attb);

    // out = sigmoid([pred|att] @ Wf + bf) -> fp32 d_out
    mfma_gemm<1, 2, 0><<<dim3(4, 128, 1), thr, 0, stream>>>(
        predb, attb, APF_D, WfT, nullptr, 2 * APF_D, bfu, nullptr, d_out, nullptr,
        APF_D, 2 * APF_D, 0, 0, 0);
}